// Round 2
// baseline (266.003 us; speedup 1.0000x reference)
//
#include <hip/hip_runtime.h>

// Patch_Embed_Rotate: per-16x16-patch conditional transpose.
// out[b,c,hi*16+i,wi*16+j] = mask[b,wi,hi] ? x[b,c,hi*16+j,wi*16+i]
//                                          : x[b,c,hi*16+i,wi*16+j]
// B=256, C=3, H=W=224, P=16.
//
// Key fact: strip (b,c,hi) = x[b,c,hi*16:(hi+1)*16,:] is a CONTIGUOUS
// 14336-byte block (rows span full W). So: stream contiguous 14 KB in
// (coalesced 1 KB/wave-instr), permute via LDS, stream contiguous 14 KB out.
// R0's per-wave patch tiles (16x 64B segments @ 896B stride, 8 KB/block,
// 37.6K blocks) ran at 1.2 TB/s; this streams like the 6.6 TB/s fill kernel.

#define NPATCH 14
#define ROWSTRIDE 228      // floats/row in LDS; multiple of 4 -> b128-aligned rows
#define NSTRIPS 10752      // B*C*h = 256*3*14
#define F4_PER_STRIP 896   // 16 rows * 224 cols / 4

__global__ __launch_bounds__(256) void patch_rotate_kernel(
    const float4* __restrict__ x,
    const int*    __restrict__ mask,
    float4*       __restrict__ out)
{
    __shared__ float lds[16 * ROWSTRIDE];   // 14592 B
    __shared__ int   smask[NPATCH];

    const int tid = threadIdx.x;

    for (int s = blockIdx.x; s < NSTRIPS; s += gridDim.x) {
        // strip s = (b*3 + c)*14 + hi
        const int hi = s % NPATCH;
        const int b  = (s / NPATCH) / 3;

        // mask[b, wi, hi] for this strip's 14 patches (W-index is 2nd dim)
        if (tid < NPATCH)
            smask[tid] = mask[(b * NPATCH + tid) * NPATCH + hi];

        // ---- load phase: contiguous 14 KB -> LDS (swizzled) ----
        const float4* __restrict__ src = x + (size_t)s * F4_PER_STRIP;
        #pragma unroll
        for (int u = tid; u < F4_PER_STRIP; u += 256) {
            const float4 v = src[u];                 // fully coalesced
            const int j  = u / 56;                   // strip row 0..15
            const int G  = u % 56;                   // global 4-col group
            const int wi = G >> 2, g = G & 3;
            // group-XOR swizzle: breaks 28-way bank conflict of the
            // transposed masked reads down to ~7-way, keeps 16B alignment
            const int gs = g ^ (j >> 2);
            *(float4*)&lds[j * ROWSTRIDE + wi * 16 + gs * 4] = v;
        }
        __syncthreads();

        // ---- store phase: assemble output rows, contiguous 14 KB out ----
        float4* __restrict__ dst = out + (size_t)s * F4_PER_STRIP;
        #pragma unroll
        for (int u = tid; u < F4_PER_STRIP; u += 256) {
            const int i  = u / 56;                   // output row 0..15
            const int G  = u % 56;
            const int wi = G >> 2, gl = G & 3;
            float4 r;
            if (smask[wi]) {
                // out(i, 16wi+4gl+e) = in(4gl+e, 16wi+i); element (j2=4gl+e,
                // col i) was stored at col 16wi + 4*((i/4)^(j2/4)) + (i%4),
                // and j2/4 == gl, so the column is the same for all e.
                const int colbase = wi * 16 + 4 * ((i >> 2) ^ gl) + (i & 3);
                r.x = lds[(4 * gl + 0) * ROWSTRIDE + colbase];
                r.y = lds[(4 * gl + 1) * ROWSTRIDE + colbase];
                r.z = lds[(4 * gl + 2) * ROWSTRIDE + colbase];
                r.w = lds[(4 * gl + 3) * ROWSTRIDE + colbase];
            } else {
                // straight copy: groups within the patch were permuted by row
                r = *(const float4*)&lds[i * ROWSTRIDE + wi * 16 +
                                         4 * (gl ^ (i >> 2))];
            }
            dst[u] = r;                              // fully coalesced
        }
        __syncthreads();   // protect lds + smask before next strip
    }
}

extern "C" void kernel_launch(void* const* d_in, const int* in_sizes, int n_in,
                              void* d_out, int out_size, void* d_ws, size_t ws_size,
                              hipStream_t stream) {
    const float4* x    = (const float4*)d_in[0];
    const int*    mask = (const int*)d_in[1];
    float4*       out  = (float4*)d_out;

    // 1792 blocks * 6 strips = 10752 exactly; 7 blocks/CU all co-resident
    // (LDS 7 * 14.6 KB = 102 KB < 160 KB), 28 waves/CU.
    patch_rotate_kernel<<<1792, 256, 0, stream>>>(x, mask, out);
}